// Round 1
// baseline (1088.965 us; speedup 1.0000x reference)
//
#include <hip/hip_runtime.h>
#include <hip/hip_bf16.h>
#include <cstdint>
#include <cstddef>

#define DEVFN __device__ __forceinline__

typedef __attribute__((ext_vector_type(4))) float f32x4;
typedef __attribute__((ext_vector_type(8))) short bf16x8;
typedef __attribute__((ext_vector_type(4))) short short4v;

static constexpr int S = 4096;
static constexpr int H = 3584;
static constexpr int NQ = 16;
static constexpr int NKV = 8;
static constexpr int D = 256;
static constexpr int WINDOW = 2048;
static constexpr float SOFTCAP = 50.0f;
static constexpr float SCALE = 0.0625f;  // 256^-0.5

DEVFN unsigned short f2bf(float f) {
  union { float f; uint32_t u; } x; x.f = f;
  uint32_t u = x.u;
  u += 0x7fffu + ((u >> 16) & 1u);   // RNE
  return (unsigned short)(u >> 16);
}
DEVFN float bf2f(unsigned short h) {
  union { uint32_t u; float f; } x; x.u = ((uint32_t)h) << 16;
  return x.f;
}

DEVFN void load_lds16(const void* g, void* l) {
  __builtin_amdgcn_global_load_lds((const __attribute__((address_space(1))) void*)g,
                                   (__attribute__((address_space(3))) void*)l,
                                   16, 0, 0);
}

// ---------------- elementwise cast: hs f32 -> bf16 ----------------
__global__ __launch_bounds__(256) void cast_hs_kernel(const float* __restrict__ in,
                                                      unsigned short* __restrict__ out) {
  int i = (blockIdx.x * 256 + threadIdx.x) * 4;
  float4 v = *(const float4*)(in + i);
  short4v o;
  o[0] = (short)f2bf(v.x); o[1] = (short)f2bf(v.y);
  o[2] = (short)f2bf(v.z); o[3] = (short)f2bf(v.w);
  *(short4v*)(out + i) = o;
}

// ---------------- transpose + cast: w[K][N] f32 -> wT[N][K] bf16 ----------------
__global__ void transpose_cast_kernel(const float* __restrict__ in, unsigned short* __restrict__ out,
                                      int rows, int cols, int out_ld) {
  __shared__ float tile[32][33];
  int r0 = blockIdx.y * 32, c0 = blockIdx.x * 32;
  int tx = threadIdx.x, ty = threadIdx.y;  // 32 x 8
#pragma unroll
  for (int j = 0; j < 32; j += 8)
    tile[ty + j][tx] = in[(size_t)(r0 + ty + j) * cols + (c0 + tx)];
  __syncthreads();
#pragma unroll
  for (int j = 0; j < 32; j += 8)
    out[(size_t)(c0 + ty + j) * out_ld + (r0 + tx)] = f2bf(tile[tx][ty + j]);
}

// ---------------- RoPE cos/sin table [S][128] x2 f32 ----------------
__global__ __launch_bounds__(256) void rope_table_kernel(float* __restrict__ cs) {
  int idx = blockIdx.x * 256 + threadIdx.x;  // S*128
  int s = idx >> 7, i = idx & 127;
  float inv = 1.0f / powf(10000.0f, (float)i * (1.0f / 128.0f));
  float f = (float)s * inv;
  cs[idx] = cosf(f);
  cs[(S * 128) + idx] = sinf(f);
}

// ---------------- RoPE apply in-place on q and k (bf16) ----------------
__global__ __launch_bounds__(256) void rope_apply_kernel(unsigned short* __restrict__ q,
                                                         unsigned short* __restrict__ k,
                                                         const float* __restrict__ cs) {
  int idx = blockIdx.x * 256 + threadIdx.x;   // (NQ+NKV)*S*128
  int i = idx & 127;
  int s = (idx >> 7) & (S - 1);
  int hh = idx >> 19;
  unsigned short* base = (hh < NQ) ? (q + ((size_t)hh * S + s) * D)
                                   : (k + ((size_t)(hh - NQ) * S + s) * D);
  float c  = cs[(s << 7) + i];
  float sn = cs[(S * 128) + (s << 7) + i];
  float x1 = bf2f(base[i]);
  float x2 = bf2f(base[i + 128]);
  base[i]       = f2bf(x1 * c - x2 * sn);
  base[i + 128] = f2bf(x2 * c + x1 * sn);
}

// ---------------- m97-style 128x128 GEMM mainloop (TN, bf16, BK=32) ----------------
// A[M][K] row-major bf16, Bt[N][K] row-major bf16. 256 threads, 4 waves (2x2 of 64x64).
// LDS tiles [128][32] bf16, XOR-swizzled via pre-swizzled global source: phys kbyte = kbyte ^ ((row&3)<<4).
DEVFN void gemm_mainloop(const unsigned short* __restrict__ A, const unsigned short* __restrict__ Bt,
                         int Kdim, int lda, int ldb, int row0, int col0,
                         char* ldsA, char* ldsB, f32x4 acc[4][4]) {
  const int tid = threadIdx.x;
  const int lane = tid & 63;
  const int w = tid >> 6;
  const int wy = w >> 1, wx = w & 1;

  // staging: 8 chunks of 1KB per tile; wave w handles chunks {w, w+4}
  const int sr  = lane >> 2;             // row within chunk (16 rows/chunk)
  const int skb = (lane & 3) * 16;       // phys in-row byte
  const int rA0 = w * 16 + sr, rA1 = (w + 4) * 16 + sr;
  const int kA0 = skb ^ ((rA0 & 3) << 4), kA1 = skb ^ ((rA1 & 3) << 4);
  const unsigned short* gA0 = A + (size_t)(row0 + rA0) * lda + (kA0 >> 1);
  const unsigned short* gA1 = A + (size_t)(row0 + rA1) * lda + (kA1 >> 1);
  const unsigned short* gB0 = Bt + (size_t)(col0 + rA0) * ldb + (kA0 >> 1);
  const unsigned short* gB1 = Bt + (size_t)(col0 + rA1) * ldb + (kA1 >> 1);
  char* lA0 = ldsA + w * 1024; char* lA1 = ldsA + (w + 4) * 1024;
  char* lB0 = ldsB + w * 1024; char* lB1 = ldsB + (w + 4) * 1024;

  // fragment read offsets: row = (wave)*64 + m*16 + (lane&15), kbyte = (lane>>4)*16 ^ ((row&3)<<4)
  const int fo = ((lane & 15) * 64) + (((lane >> 4) * 16) ^ ((lane & 3) << 4));
  const char* fA = ldsA + wy * 64 * 64 + fo;
  const char* fB = ldsB + wx * 64 * 64 + fo;

  for (int k0 = 0; k0 < Kdim; k0 += 32) {
    load_lds16(gA0, lA0); load_lds16(gA1, lA1);
    load_lds16(gB0, lB0); load_lds16(gB1, lB1);
    gA0 += 32; gA1 += 32; gB0 += 32; gB1 += 32;
    __syncthreads();
    bf16x8 af[4], bfr[4];
#pragma unroll
    for (int m = 0; m < 4; ++m) af[m] = *(const bf16x8*)(fA + m * 1024);
#pragma unroll
    for (int n = 0; n < 4; ++n) bfr[n] = *(const bf16x8*)(fB + n * 1024);
#pragma unroll
    for (int m = 0; m < 4; ++m)
#pragma unroll
      for (int n = 0; n < 4; ++n)
        acc[m][n] = __builtin_amdgcn_mfma_f32_16x16x32_bf16(af[m], bfr[n], acc[m][n], 0, 0, 0);
    __syncthreads();
  }
}

// ---------------- GEMM 1: [S][H] x [H][8192] -> scatter to q, k, vt ----------------
__global__ __launch_bounds__(256) void gemm_qkv_kernel(const unsigned short* __restrict__ A,
                                                       const unsigned short* __restrict__ Bt,
                                                       unsigned short* __restrict__ qb,
                                                       unsigned short* __restrict__ kbuf,
                                                       unsigned short* __restrict__ vtb) {
  __shared__ __align__(16) char ldsA[8192];
  __shared__ __align__(16) char ldsB[8192];
  const int nbx = S / 128;  // 32
  int bid = blockIdx.x;
  const int cpx = 2048 / 8;
  bid = (bid & 7) * cpx + (bid >> 3);   // bijective XCD swizzle (2048 % 8 == 0)
  const int bx = bid % nbx, by = bid / nbx;
  const int row0 = bx * 128, col0 = by * 128;
  f32x4 acc[4][4];
  f32x4 z = {0.f, 0.f, 0.f, 0.f};
#pragma unroll
  for (int m = 0; m < 4; ++m)
#pragma unroll
    for (int n = 0; n < 4; ++n) acc[m][n] = z;

  gemm_mainloop(A, Bt, H, H, H, row0, col0, ldsA, ldsB, acc);

  const int lane = threadIdx.x & 63, w = threadIdx.x >> 6;
  const int wy = w >> 1, wx = w & 1;
#pragma unroll
  for (int m = 0; m < 4; ++m)
#pragma unroll
    for (int n = 0; n < 4; ++n)
#pragma unroll
      for (int r = 0; r < 4; ++r) {
        int row = row0 + wy * 64 + m * 16 + (lane >> 4) * 4 + r;  // seq
        int col = col0 + wx * 64 + n * 16 + (lane & 15);
        unsigned short v = f2bf(acc[m][n][r]);
        if (col < NQ * D) {
          qb[((size_t)(col >> 8) * S + row) * D + (col & 255)] = v;
        } else if (col < (NQ + NKV) * D) {
          int c2 = col - NQ * D;
          kbuf[((size_t)(c2 >> 8) * S + row) * D + (c2 & 255)] = v;
        } else {
          int c3 = col - (NQ + NKV) * D;
          vtb[((size_t)(c3 >> 8) * D + (c3 & 255)) * S + row] = v;  // V transposed
        }
      }
}

// ---------------- GEMM 2: attn_out[S][4096] x woT[H][4096] -> d_out f32 [S][H] ----------------
__global__ __launch_bounds__(256) void gemm_out_kernel(const unsigned short* __restrict__ A,
                                                       const unsigned short* __restrict__ Bt,
                                                       float* __restrict__ C) {
  __shared__ __align__(16) char ldsA[8192];
  __shared__ __align__(16) char ldsB[8192];
  const int nbx = S / 128;  // 32
  int bid = blockIdx.x;
  const int nwg = (S / 128) * (H / 128);  // 896
  const int cpx = nwg / 8;
  bid = (bid & 7) * cpx + (bid >> 3);
  const int bx = bid % nbx, by = bid / nbx;
  const int row0 = bx * 128, col0 = by * 128;
  f32x4 acc[4][4];
  f32x4 z = {0.f, 0.f, 0.f, 0.f};
#pragma unroll
  for (int m = 0; m < 4; ++m)
#pragma unroll
    for (int n = 0; n < 4; ++n) acc[m][n] = z;

  gemm_mainloop(A, Bt, NQ * D, NQ * D, NQ * D, row0, col0, ldsA, ldsB, acc);

  const int lane = threadIdx.x & 63, w = threadIdx.x >> 6;
  const int wy = w >> 1, wx = w & 1;
#pragma unroll
  for (int m = 0; m < 4; ++m)
#pragma unroll
    for (int n = 0; n < 4; ++n)
#pragma unroll
      for (int r = 0; r < 4; ++r) {
        int row = row0 + wy * 64 + m * 16 + (lane >> 4) * 4 + r;
        int col = col0 + wx * 64 + n * 16 + (lane & 15);
        C[(size_t)row * H + col] = acc[m][n][r];
      }
}

// ---------------- flash attention, sliding window + softcap, GQA ----------------
// grid (S/64, NQ), 256 threads. Wave w handles q cols [q0+w*16, +16).
// Swapped QK^T: scores^T = mfma(K, Q) so softmax rows are lane-local-ish (2 shfl_xor).
__global__ __launch_bounds__(256) void attn_kernel(const unsigned short* __restrict__ q,
                                                   const unsigned short* __restrict__ kk_,
                                                   const unsigned short* __restrict__ vt,
                                                   unsigned short* __restrict__ aout) {
  __shared__ __align__(16) char kl[32768];  // K tile [64][256] bf16, swizzled
  __shared__ __align__(16) char vl[32768];  // Vt tile [256][64] bf16, swizzled
  __shared__ __align__(16) char pl[8192];   // P^T per wave [16 q][64 key] bf16, swizzled
  const int tid = threadIdx.x, lane = tid & 63, w = tid >> 6;
  const int h = blockIdx.y, hv = h >> 1;    // N_REP = 2
  const int q0 = blockIdx.x * 64;
  const int ql = lane & 15;   // q col within wave tile
  const int grp = lane >> 4;  // 0..3
  const int qg = q0 + w * 16 + ql;

  // hoist Q fragments: B-frag for kstep t: Q[q][t*32 + grp*8 + j]
  bf16x8 qf[8];
  const unsigned short* qrow = q + ((size_t)h * S + qg) * D;
#pragma unroll
  for (int t = 0; t < 8; ++t)
    qf[t] = *(const bf16x8*)(qrow + t * 32 + grp * 8);

  f32x4 oacc[16];  // O^T: d rows (16 tiles of 16), q col = ql
  f32x4 z = {0.f, 0.f, 0.f, 0.f};
#pragma unroll
  for (int i = 0; i < 16; ++i) oacc[i] = z;
  float mrun = -1e30f, lrun = 0.0f;

  int lo = q0 - (WINDOW - 1); if (lo < 0) lo = 0;
  const int kb0 = lo & ~63;

  for (int kb = kb0; kb <= q0; kb += 64) {
    // stage K [64][256] and Vt [256][64]; 32 chunks of 1KB each; wave w: chunks w+4j
#pragma unroll
    for (int j = 0; j < 8; ++j) {
      int c = w + 4 * j;
      int key = c * 2 + (lane >> 5);
      int d2 = ((lane & 31) * 16) ^ ((key & 7) << 4);
      load_lds16(kk_ + ((size_t)hv * S + kb + key) * D + (d2 >> 1), kl + c * 1024);
      int dd = c * 8 + (lane >> 3);
      int k2 = ((lane & 7) * 16) ^ ((dd & 7) << 4);
      load_lds16(vt + ((size_t)hv * D + dd) * S + kb + (k2 >> 1), vl + c * 1024);
    }
    __syncthreads();

    // scores^T = K(64x256) x Q^T(256x16): rows=keys, cols=q
    f32x4 sacc[4];
#pragma unroll
    for (int mt = 0; mt < 4; ++mt) sacc[mt] = z;
#pragma unroll
    for (int mt = 0; mt < 4; ++mt) {
      int krow = mt * 16 + ql;
      const char* kbase = kl + krow * 512;
#pragma unroll
      for (int t = 0; t < 8; ++t) {
        bf16x8 a = *(const bf16x8*)(kbase + ((t * 64 + grp * 16) ^ ((krow & 7) << 4)));
        sacc[mt] = __builtin_amdgcn_mfma_f32_16x16x32_bf16(a, qf[t], sacc[mt], 0, 0, 0);
      }
    }

    // softcap + mask + online softmax (per lane: 16 keys for q col = ql)
    float sv[16];
    float pm = -1e30f;
#pragma unroll
    for (int mt = 0; mt < 4; ++mt)
#pragma unroll
      for (int r = 0; r < 4; ++r) {
        int key = kb + mt * 16 + grp * 4 + r;
        float s = sacc[mt][r] * SCALE;
        float e = __expf(s * (2.0f / SOFTCAP));
        s = SOFTCAP * (1.0f - 2.0f / (e + 1.0f));   // 50*tanh(s/50)
        bool valid = (key <= qg) && (key > qg - WINDOW);
        s = valid ? s : -1e30f;
        sv[mt * 4 + r] = s;
        pm = fmaxf(pm, s);
      }
    pm = fmaxf(pm, __shfl_xor(pm, 16));
    pm = fmaxf(pm, __shfl_xor(pm, 32));
    float mnew = fmaxf(mrun, pm);
    float corr = __expf(mrun - mnew);
    float rs = 0.0f;
#pragma unroll
    for (int i = 0; i < 16; ++i) { float p = __expf(sv[i] - mnew); sv[i] = p; rs += p; }
    rs += __shfl_xor(rs, 16);
    rs += __shfl_xor(rs, 32);
    lrun = lrun * corr + rs;
    mrun = mnew;
#pragma unroll
    for (int i = 0; i < 16; ++i) oacc[i] *= corr;

    // P^T -> LDS (per-wave region), bf16, swizzled rows of 128B
    char* pw = pl + w * 2048;
#pragma unroll
    for (int mt = 0; mt < 4; ++mt) {
      short4v pk;
      pk[0] = (short)f2bf(sv[mt * 4 + 0]);
      pk[1] = (short)f2bf(sv[mt * 4 + 1]);
      pk[2] = (short)f2bf(sv[mt * 4 + 2]);
      pk[3] = (short)f2bf(sv[mt * 4 + 3]);
      int a = ql * 128 + mt * 32 + grp * 8;
      *(short4v*)(pw + (a ^ ((ql & 7) << 4))) = pk;
    }
    asm volatile("s_waitcnt lgkmcnt(0)" ::: "memory");  // wave-internal RAW on P lds

    // O^T += Vt(256x64) x P^T(64x16)
#pragma unroll
    for (int ks = 0; ks < 2; ++ks) {
      bf16x8 pb = *(const bf16x8*)(pw + ((ql * 128 + ks * 64 + grp * 16) ^ ((ql & 7) << 4)));
#pragma unroll
      for (int nt = 0; nt < 16; ++nt) {
        int dr = nt * 16 + ql;
        bf16x8 va = *(const bf16x8*)(vl + dr * 128 + ((ks * 64 + grp * 16) ^ ((dr & 7) << 4)));
        oacc[nt] = __builtin_amdgcn_mfma_f32_16x16x32_bf16(va, pb, oacc[nt], 0, 0, 0);
      }
    }
    __syncthreads();
  }

  // epilogue: normalize, write attn_out[s][h*256 + d] bf16
  float rl = 1.0f / lrun;
  unsigned short* orow = aout + (size_t)qg * (NQ * D) + h * D;
#pragma unroll
  for (int nt = 0; nt < 16; ++nt) {
    short4v o;
    o[0] = (short)f2bf(oacc[nt][0] * rl);
    o[1] = (short)f2bf(oacc[nt][1] * rl);
    o[2] = (short)f2bf(oacc[nt][2] * rl);
    o[3] = (short)f2bf(oacc[nt][3] * rl);
    *(short4v*)(orow + nt * 16 + grp * 4) = o;
  }
}

// ---------------- launch ----------------
extern "C" void kernel_launch(void* const* d_in, const int* in_sizes, int n_in,
                              void* d_out, int out_size, void* d_ws, size_t ws_size,
                              hipStream_t stream) {
  const float* hs = (const float*)d_in[0];
  const float* wq = (const float*)d_in[1];
  const float* wk = (const float*)d_in[2];
  const float* wv = (const float*)d_in[3];
  const float* wo = (const float*)d_in[4];
  float* out = (float*)d_out;

  char* ws = (char*)d_ws;
  size_t off = 0;
  auto alloc = [&](size_t bytes) {
    char* p = ws + off;
    off += (bytes + 255) & ~(size_t)255;
    return p;
  };
  unsigned short* hsb   = (unsigned short*)alloc((size_t)S * H * 2);
  unsigned short* wqkvT = (unsigned short*)alloc((size_t)8192 * H * 2);  // rows: q 0..4095, k 4096..6143, v 6144..8191
  unsigned short* woT   = (unsigned short*)alloc((size_t)H * 4096 * 2);
  unsigned short* qb    = (unsigned short*)alloc((size_t)NQ * S * D * 2);
  unsigned short* kbuf  = (unsigned short*)alloc((size_t)NKV * S * D * 2);
  unsigned short* vtb   = (unsigned short*)alloc((size_t)NKV * D * S * 2);
  unsigned short* aob   = (unsigned short*)alloc((size_t)S * NQ * D * 2);
  float*          cs    = (float*)alloc((size_t)S * 128 * 2 * 4);
  if (off > ws_size) return;  // workspace too small: fail loudly via validation

  dim3 tb(32, 8);
  cast_hs_kernel<<<(S * H) / 1024, 256, 0, stream>>>(hs, hsb);
  transpose_cast_kernel<<<dim3(4096 / 32, H / 32), tb, 0, stream>>>(wq, wqkvT, H, 4096, H);
  transpose_cast_kernel<<<dim3(2048 / 32, H / 32), tb, 0, stream>>>(wk, wqkvT + (size_t)4096 * H, H, 2048, H);
  transpose_cast_kernel<<<dim3(2048 / 32, H / 32), tb, 0, stream>>>(wv, wqkvT + (size_t)6144 * H, H, 2048, H);
  transpose_cast_kernel<<<dim3(H / 32, 4096 / 32), tb, 0, stream>>>(wo, woT, 4096, H, 4096);
  rope_table_kernel<<<(S * 128) / 256, 256, 0, stream>>>(cs);
  gemm_qkv_kernel<<<2048, 256, 0, stream>>>(hsb, wqkvT, qb, kbuf, vtb);
  rope_apply_kernel<<<((NQ + NKV) * S * 128) / 256, 256, 0, stream>>>(qb, kbuf, cs);
  attn_kernel<<<dim3(S / 64, NQ), 256, 0, stream>>>(qb, kbuf, vtb, aob);
  gemm_out_kernel<<<(S / 128) * (H / 128), 256, 0, stream>>>(aob, woT, out);
}

// Round 2
// 922.327 us; speedup vs baseline: 1.1807x; 1.1807x over previous
//
#include <hip/hip_runtime.h>
#include <hip/hip_bf16.h>
#include <cstdint>
#include <cstddef>

#define DEVFN __device__ __forceinline__

typedef __attribute__((ext_vector_type(4))) float f32x4;
typedef __attribute__((ext_vector_type(8))) short bf16x8;
typedef __attribute__((ext_vector_type(4))) short short4v;

static constexpr int S = 4096;
static constexpr int H = 3584;
static constexpr int NQ = 16;
static constexpr int NKV = 8;
static constexpr int D = 256;
static constexpr int WINDOW = 2048;
static constexpr float SCALE = 0.0625f;  // 256^-0.5

DEVFN unsigned short f2bf(float f) {
  union { float f; uint32_t u; } x; x.f = f;
  uint32_t u = x.u;
  u += 0x7fffu + ((u >> 16) & 1u);   // RNE
  return (unsigned short)(u >> 16);
}
DEVFN float bf2f(unsigned short h) {
  union { uint32_t u; float f; } x; x.u = ((uint32_t)h) << 16;
  return x.f;
}

DEVFN void load_lds16(const void* g, void* l) {
  __builtin_amdgcn_global_load_lds((const __attribute__((address_space(1))) void*)g,
                                   (__attribute__((address_space(3))) void*)l,
                                   16, 0, 0);
}

// ---------------- elementwise cast: hs f32 -> bf16 ----------------
__global__ __launch_bounds__(256) void cast_hs_kernel(const float* __restrict__ in,
                                                      unsigned short* __restrict__ out) {
  int i = (blockIdx.x * 256 + threadIdx.x) * 4;
  float4 v = *(const float4*)(in + i);
  short4v o;
  o[0] = (short)f2bf(v.x); o[1] = (short)f2bf(v.y);
  o[2] = (short)f2bf(v.z); o[3] = (short)f2bf(v.w);
  *(short4v*)(out + i) = o;
}

// ---------------- transpose + cast: w[K][N] f32 -> wT[N][K] bf16 ----------------
__global__ void transpose_cast_kernel(const float* __restrict__ in, unsigned short* __restrict__ out,
                                      int rows, int cols, int out_ld) {
  __shared__ float tile[32][33];
  int r0 = blockIdx.y * 32, c0 = blockIdx.x * 32;
  int tx = threadIdx.x, ty = threadIdx.y;  // 32 x 8
#pragma unroll
  for (int j = 0; j < 32; j += 8)
    tile[ty + j][tx] = in[(size_t)(r0 + ty + j) * cols + (c0 + tx)];
  __syncthreads();
#pragma unroll
  for (int j = 0; j < 32; j += 8)
    out[(size_t)(c0 + ty + j) * out_ld + (r0 + tx)] = f2bf(tile[tx][ty + j]);
}

// ---------------- RoPE cos/sin table [S][128] x2 f32 ----------------
__global__ __launch_bounds__(256) void rope_table_kernel(float* __restrict__ cs) {
  int idx = blockIdx.x * 256 + threadIdx.x;  // S*128
  int s = idx >> 7, i = idx & 127;
  float inv = 1.0f / powf(10000.0f, (float)i * (1.0f / 128.0f));
  float f = (float)s * inv;
  cs[idx] = cosf(f);
  cs[(S * 128) + idx] = sinf(f);
}

// ---------------- RoPE apply in-place on q and k (bf16), 4 elems/thread ----------------
__global__ __launch_bounds__(256) void rope_apply_kernel(unsigned short* __restrict__ q,
                                                         unsigned short* __restrict__ k,
                                                         const float* __restrict__ cs) {
  int idx = blockIdx.x * 256 + threadIdx.x;   // (NQ+NKV)*S*32
  int i4 = (idx & 31) * 4;
  int s = (idx >> 5) & (S - 1);
  int hh = idx >> 17;
  unsigned short* base = (hh < NQ) ? (q + ((size_t)hh * S + s) * D)
                                   : (k + ((size_t)(hh - NQ) * S + s) * D);
  float4 c  = *(const float4*)(cs + (s << 7) + i4);
  float4 sn = *(const float4*)(cs + (S * 128) + (s << 7) + i4);
  short4v a = *(short4v*)(base + i4);
  short4v b = *(short4v*)(base + i4 + 128);
  short4v o1, o2;
  o1[0] = (short)f2bf(bf2f((unsigned short)a[0]) * c.x - bf2f((unsigned short)b[0]) * sn.x);
  o1[1] = (short)f2bf(bf2f((unsigned short)a[1]) * c.y - bf2f((unsigned short)b[1]) * sn.y);
  o1[2] = (short)f2bf(bf2f((unsigned short)a[2]) * c.z - bf2f((unsigned short)b[2]) * sn.z);
  o1[3] = (short)f2bf(bf2f((unsigned short)a[3]) * c.w - bf2f((unsigned short)b[3]) * sn.w);
  o2[0] = (short)f2bf(bf2f((unsigned short)b[0]) * c.x + bf2f((unsigned short)a[0]) * sn.x);
  o2[1] = (short)f2bf(bf2f((unsigned short)b[1]) * c.y + bf2f((unsigned short)a[1]) * sn.y);
  o2[2] = (short)f2bf(bf2f((unsigned short)b[2]) * c.z + bf2f((unsigned short)a[2]) * sn.z);
  o2[3] = (short)f2bf(bf2f((unsigned short)b[3]) * c.w + bf2f((unsigned short)a[3]) * sn.w);
  *(short4v*)(base + i4) = o1;
  *(short4v*)(base + i4 + 128) = o2;
}

// ---------------- 128x128 GEMM mainloop (TN, bf16, BK=32), 2-phase double-buffered ----------------
// A[M][K] row-major bf16, Bt[N][K] row-major bf16. 256 threads, 4 waves (2x2 of 64x64).
// LDS tiles 2x[128][32] bf16, XOR-swizzled via pre-swizzled global source.
DEVFN void gemm_mainloop(const unsigned short* __restrict__ A, const unsigned short* __restrict__ Bt,
                         int Kdim, int lda, int ldb, int row0, int col0,
                         char* ldsA, char* ldsB, f32x4 acc[4][4]) {
  const int tid = threadIdx.x;
  const int lane = tid & 63;
  const int w = tid >> 6;
  const int wy = w >> 1, wx = w & 1;

  const int sr  = lane >> 2;
  const int skb = (lane & 3) * 16;
  const int rA0 = w * 16 + sr, rA1 = (w + 4) * 16 + sr;
  const int kA0 = skb ^ ((rA0 & 3) << 4), kA1 = skb ^ ((rA1 & 3) << 4);
  const unsigned short* gA0 = A + (size_t)(row0 + rA0) * lda + (kA0 >> 1);
  const unsigned short* gA1 = A + (size_t)(row0 + rA1) * lda + (kA1 >> 1);
  const unsigned short* gB0 = Bt + (size_t)(col0 + rA0) * ldb + (kA0 >> 1);
  const unsigned short* gB1 = Bt + (size_t)(col0 + rA1) * ldb + (kA1 >> 1);
  const int dc0 = w * 1024, dc1 = (w + 4) * 1024;

  const int fo = ((lane & 15) * 64) + (((lane >> 4) * 16) ^ ((lane & 3) << 4));

  // prologue: stage tile 0 into buf 0
  load_lds16(gA0, ldsA + dc0); load_lds16(gA1, ldsA + dc1);
  load_lds16(gB0, ldsB + dc0); load_lds16(gB1, ldsB + dc1);
  gA0 += 32; gA1 += 32; gB0 += 32; gB1 += 32;

  int cur = 0;
  for (int k0 = 0; k0 < Kdim; k0 += 32) {
    __syncthreads();
    if (k0 + 32 < Kdim) {
      int nb = (cur ^ 1) * 8192;
      load_lds16(gA0, ldsA + nb + dc0); load_lds16(gA1, ldsA + nb + dc1);
      load_lds16(gB0, ldsB + nb + dc0); load_lds16(gB1, ldsB + nb + dc1);
      gA0 += 32; gA1 += 32; gB0 += 32; gB1 += 32;
    }
    const char* fA = ldsA + cur * 8192 + wy * 4096 + fo;
    const char* fB = ldsB + cur * 8192 + wx * 4096 + fo;
    bf16x8 af[4], bfr[4];
#pragma unroll
    for (int m = 0; m < 4; ++m) af[m] = *(const bf16x8*)(fA + m * 1024);
#pragma unroll
    for (int n = 0; n < 4; ++n) bfr[n] = *(const bf16x8*)(fB + n * 1024);
#pragma unroll
    for (int m = 0; m < 4; ++m)
#pragma unroll
      for (int n = 0; n < 4; ++n)
        acc[m][n] = __builtin_amdgcn_mfma_f32_16x16x32_bf16(af[m], bfr[n], acc[m][n], 0, 0, 0);
    cur ^= 1;
  }
}

// ---------------- GEMM 1: [S][H] x [H][8192] -> scatter to q, k, vt ----------------
__global__ __launch_bounds__(256) void gemm_qkv_kernel(const unsigned short* __restrict__ A,
                                                       const unsigned short* __restrict__ Bt,
                                                       unsigned short* __restrict__ qb,
                                                       unsigned short* __restrict__ kbuf,
                                                       unsigned short* __restrict__ vtb) {
  __shared__ __align__(16) char ldsA[2][8192];
  __shared__ __align__(16) char ldsB[2][8192];
  const int nbx = S / 128;  // 32
  int bid = blockIdx.x;
  const int cpx = 2048 / 8;
  bid = (bid & 7) * cpx + (bid >> 3);   // bijective XCD swizzle (2048 % 8 == 0)
  const int bx = bid % nbx, by = bid / nbx;
  const int row0 = bx * 128, col0 = by * 128;
  f32x4 acc[4][4];
  f32x4 z = {0.f, 0.f, 0.f, 0.f};
#pragma unroll
  for (int m = 0; m < 4; ++m)
#pragma unroll
    for (int n = 0; n < 4; ++n) acc[m][n] = z;

  gemm_mainloop(A, Bt, H, H, H, row0, col0, &ldsA[0][0], &ldsB[0][0], acc);

  const int lane = threadIdx.x & 63, w = threadIdx.x >> 6;
  const int wy = w >> 1, wx = w & 1;
#pragma unroll
  for (int m = 0; m < 4; ++m)
#pragma unroll
    for (int n = 0; n < 4; ++n)
#pragma unroll
      for (int r = 0; r < 4; ++r) {
        int row = row0 + wy * 64 + m * 16 + (lane >> 4) * 4 + r;  // seq
        int col = col0 + wx * 64 + n * 16 + (lane & 15);
        unsigned short v = f2bf(acc[m][n][r]);
        if (col < NQ * D) {
          qb[((size_t)(col >> 8) * S + row) * D + (col & 255)] = v;
        } else if (col < (NQ + NKV) * D) {
          int c2 = col - NQ * D;
          kbuf[((size_t)(c2 >> 8) * S + row) * D + (c2 & 255)] = v;
        } else {
          int c3 = col - (NQ + NKV) * D;
          vtb[((size_t)(c3 >> 8) * D + (c3 & 255)) * S + row] = v;  // V transposed
        }
      }
}

// ---------------- GEMM 2: attn_out[S][4096] x woT[H][4096] -> d_out f32 [S][H] ----------------
__global__ __launch_bounds__(256) void gemm_out_kernel(const unsigned short* __restrict__ A,
                                                       const unsigned short* __restrict__ Bt,
                                                       float* __restrict__ C) {
  __shared__ __align__(16) char ldsA[2][8192];
  __shared__ __align__(16) char ldsB[2][8192];
  const int nbx = S / 128;  // 32
  int bid = blockIdx.x;
  const int nwg = (S / 128) * (H / 128);  // 896
  const int cpx = nwg / 8;
  bid = (bid & 7) * cpx + (bid >> 3);
  const int bx = bid % nbx, by = bid / nbx;
  const int row0 = bx * 128, col0 = by * 128;
  f32x4 acc[4][4];
  f32x4 z = {0.f, 0.f, 0.f, 0.f};
#pragma unroll
  for (int m = 0; m < 4; ++m)
#pragma unroll
    for (int n = 0; n < 4; ++n) acc[m][n] = z;

  gemm_mainloop(A, Bt, NQ * D, NQ * D, NQ * D, row0, col0, &ldsA[0][0], &ldsB[0][0], acc);

  const int lane = threadIdx.x & 63, w = threadIdx.x >> 6;
  const int wy = w >> 1, wx = w & 1;
#pragma unroll
  for (int m = 0; m < 4; ++m)
#pragma unroll
    for (int n = 0; n < 4; ++n)
#pragma unroll
      for (int r = 0; r < 4; ++r) {
        int row = row0 + wy * 64 + m * 16 + (lane >> 4) * 4 + r;
        int col = col0 + wx * 64 + n * 16 + (lane & 15);
        C[(size_t)row * H + col] = acc[m][n][r];
      }
}

// ---------------- flash attention, sliding window + softcap, GQA ----------------
// grid (S/64, NQ), 256 threads, wave w owns q cols [q0+w*16, +16).
// KVBLK=32, double-buffered K/V, 2-phase pipeline (stage next || compute cur),
// fixed-max softmax: softcap bounds s to +-50 so P = exp(s-50) needs no running max.
__global__ __launch_bounds__(256) void attn_kernel(const unsigned short* __restrict__ q,
                                                   const unsigned short* __restrict__ kk_,
                                                   const unsigned short* __restrict__ vt,
                                                   unsigned short* __restrict__ aout) {
  __shared__ __align__(16) char kl[2][16384];  // K tile [32 keys][256 d] bf16, swizzled
  __shared__ __align__(16) char vl[2][16384];  // Vt tile [256 d][32 keys] bf16, swizzled
  __shared__ __align__(16) char pl[4096];      // P per wave [16 q][32 keys] bf16, swizzled
  const int tid = threadIdx.x, lane = tid & 63, w = tid >> 6;
  const int h = blockIdx.y, hv = h >> 1;    // N_REP = 2
  const int q0 = blockIdx.x * 64;
  const int ql = lane & 15;
  const int grp = lane >> 4;
  const int qg = q0 + w * 16 + ql;

  // hoist Q fragments (B-operand of QK^T)
  bf16x8 qf[8];
  const unsigned short* qrow = q + ((size_t)h * S + qg) * D;
#pragma unroll
  for (int t = 0; t < 8; ++t)
    qf[t] = *(const bf16x8*)(qrow + t * 32 + grp * 8);

  f32x4 oacc[16];  // O^T: d rows (16 tiles of 16), q col = ql
  f32x4 z = {0.f, 0.f, 0.f, 0.f};
#pragma unroll
  for (int i = 0; i < 16; ++i) oacc[i] = z;
  float lrun = 0.0f;

  int lo = q0 - (WINDOW - 1); if (lo < 0) lo = 0;
  const int kb0 = lo & ~31;
  const int kend = q0 + 32;

  // loop-invariant staging offsets: wave w stages chunks {w+4j}, j=0..3, of K and Vt
  const unsigned short* kbase = kk_ + (size_t)hv * S * D;
  const unsigned short* vbase = vt + (size_t)hv * D * S;
  int koff[4], voff[4];
#pragma unroll
  for (int j = 0; j < 4; ++j) {
    int c = w + 4 * j;
    int key = c * 2 + (lane >> 5);
    int colK = (((lane & 31) * 16) ^ ((key & 7) << 4)) >> 1;
    koff[j] = key * D + colK;
    int dd = c * 16 + (lane >> 2);
    int colV = (((lane & 3) * 16) ^ (((dd >> 1) & 3) << 4)) >> 1;
    voff[j] = dd * S + colV;
  }

  auto stage = [&](int buf, int kb) {
#pragma unroll
    for (int j = 0; j < 4; ++j) {
      int c = w + 4 * j;
      load_lds16(kbase + (size_t)kb * D + koff[j], &kl[buf][c * 1024]);
      load_lds16(vbase + kb + voff[j], &vl[buf][c * 1024]);
    }
  };

  stage(0, kb0);
  int cur = 0;
  const int psw = ((ql >> 1) & 3) << 4;
  char* pw = pl + w * 1024;

  for (int kb = kb0; kb <= kend; kb += 32) {
    __syncthreads();                       // staged loads for buf[cur] drained; buf[cur^1] free
    if (kb + 32 <= kend) stage(cur ^ 1, kb + 32);

    // scores^T = K(32x256) x Q^T(256x16)
    f32x4 sacc[2];
    sacc[0] = z; sacc[1] = z;
#pragma unroll
    for (int mt = 0; mt < 2; ++mt) {
      const int krow = mt * 16 + ql;
      const char* kbp = kl[cur] + krow * 512;
      const int sw = (krow & 7) << 4;
#pragma unroll
      for (int t = 0; t < 8; ++t) {
        bf16x8 a = *(const bf16x8*)(kbp + ((t * 64 + grp * 16) ^ sw));
        sacc[mt] = __builtin_amdgcn_mfma_f32_16x16x32_bf16(a, qf[t], sacc[mt], 0, 0, 0);
      }
    }

    // fused softcap+softmax vs fixed max 50: p = exp(-100 / (exp(x*SCALE/25) + 1))
    float pv[8];
#pragma unroll
    for (int i = 0; i < 8; ++i) {
      float x = sacc[i >> 2][i & 3];
      float e = __expf(x * (SCALE / 25.0f));
      float rc = __builtin_amdgcn_rcpf(e + 1.0f);
      pv[i] = __expf(rc * -100.0f);
    }
    if (kb + 31 > q0) {                    // causal edge tiles
#pragma unroll
      for (int i = 0; i < 8; ++i) {
        int key = kb + (i >> 2) * 16 + grp * 4 + (i & 3);
        if (key > qg) pv[i] = 0.0f;
      }
    } else if (kb < q0 - (WINDOW - 64)) {  // window edge tiles
#pragma unroll
      for (int i = 0; i < 8; ++i) {
        int key = kb + (i >> 2) * 16 + grp * 4 + (i & 3);
        if (key <= qg - WINDOW) pv[i] = 0.0f;
      }
    }
#pragma unroll
    for (int i = 0; i < 8; ++i) lrun += pv[i];

    // P -> per-wave LDS ([16 q][32 k] rows of 64B, 16B-slot swizzle by (ql>>1)&3)
#pragma unroll
    for (int mt = 0; mt < 2; ++mt) {
      short4v pk;
      pk[0] = (short)f2bf(pv[mt * 4 + 0]);
      pk[1] = (short)f2bf(pv[mt * 4 + 1]);
      pk[2] = (short)f2bf(pv[mt * 4 + 2]);
      pk[3] = (short)f2bf(pv[mt * 4 + 3]);
      *(short4v*)(pw + ql * 64 + ((mt * 32 + grp * 8) ^ psw)) = pk;
    }
    asm volatile("s_waitcnt lgkmcnt(0)" ::: "memory");
    bf16x8 pb = *(const bf16x8*)(pw + ql * 64 + ((grp * 16) ^ psw));

    // O^T += Vt(256x32) x P^T(32x16)
#pragma unroll
    for (int nt = 0; nt < 16; ++nt) {
      int dr = nt * 16 + ql;
      bf16x8 va = *(const bf16x8*)(vl[cur] + dr * 64 + ((grp * 16) ^ (((dr >> 1) & 3) << 4)));
      oacc[nt] = __builtin_amdgcn_mfma_f32_16x16x32_bf16(va, pb, oacc[nt], 0, 0, 0);
    }
    cur ^= 1;
  }

  // epilogue: reduce l across the 4 lane-groups (same q), normalize, store
  lrun += __shfl_xor(lrun, 16);
  lrun += __shfl_xor(lrun, 32);
  lrun = fmaxf(lrun, 1e-35f);
  float rl = 1.0f / lrun;
  unsigned short* orow = aout + (size_t)qg * (NQ * D) + h * D;
#pragma unroll
  for (int nt = 0; nt < 16; ++nt) {
    short4v o;
    o[0] = (short)f2bf(oacc[nt][0] * rl);
    o[1] = (short)f2bf(oacc[nt][1] * rl);
    o[2] = (short)f2bf(oacc[nt][2] * rl);
    o[3] = (short)f2bf(oacc[nt][3] * rl);
    *(short4v*)(orow + nt * 16 + grp * 4) = o;
  }
}

// ---------------- launch ----------------
extern "C" void kernel_launch(void* const* d_in, const int* in_sizes, int n_in,
                              void* d_out, int out_size, void* d_ws, size_t ws_size,
                              hipStream_t stream) {
  const float* hs = (const float*)d_in[0];
  const float* wq = (const float*)d_in[1];
  const float* wk = (const float*)d_in[2];
  const float* wv = (const float*)d_in[3];
  const float* wo = (const float*)d_in[4];
  float* out = (float*)d_out;

  char* ws = (char*)d_ws;
  size_t off = 0;
  auto alloc = [&](size_t bytes) {
    char* p = ws + off;
    off += (bytes + 255) & ~(size_t)255;
    return p;
  };
  unsigned short* hsb   = (unsigned short*)alloc((size_t)S * H * 2);
  unsigned short* wqkvT = (unsigned short*)alloc((size_t)8192 * H * 2);
  unsigned short* woT   = (unsigned short*)alloc((size_t)H * 4096 * 2);
  unsigned short* qb    = (unsigned short*)alloc((size_t)NQ * S * D * 2);
  unsigned short* kbuf  = (unsigned short*)alloc((size_t)NKV * S * D * 2);
  unsigned short* vtb   = (unsigned short*)alloc((size_t)NKV * D * S * 2);
  unsigned short* aob   = (unsigned short*)alloc((size_t)S * NQ * D * 2);
  float*          cs    = (float*)alloc((size_t)S * 128 * 2 * 4);
  if (off > ws_size) return;

  dim3 tb(32, 8);
  cast_hs_kernel<<<(S * H) / 1024, 256, 0, stream>>>(hs, hsb);
  transpose_cast_kernel<<<dim3(4096 / 32, H / 32), tb, 0, stream>>>(wq, wqkvT, H, 4096, H);
  transpose_cast_kernel<<<dim3(2048 / 32, H / 32), tb, 0, stream>>>(wk, wqkvT + (size_t)4096 * H, H, 2048, H);
  transpose_cast_kernel<<<dim3(2048 / 32, H / 32), tb, 0, stream>>>(wv, wqkvT + (size_t)6144 * H, H, 2048, H);
  transpose_cast_kernel<<<dim3(H / 32, 4096 / 32), tb, 0, stream>>>(wo, woT, 4096, H, 4096);
  rope_table_kernel<<<(S * 128) / 256, 256, 0, stream>>>(cs);
  gemm_qkv_kernel<<<2048, 256, 0, stream>>>(hsb, wqkvT, qb, kbuf, vtb);
  rope_apply_kernel<<<((NQ + NKV) * S * 32) / 256, 256, 0, stream>>>(qb, kbuf, cs);
  attn_kernel<<<dim3(S / 64, NQ), 256, 0, stream>>>(qb, kbuf, vtb, aob);
  gemm_out_kernel<<<(S / 128) * (H / 128), 256, 0, stream>>>(aob, woT, out);
}

// Round 3
// 650.263 us; speedup vs baseline: 1.6747x; 1.4184x over previous
//
#include <hip/hip_runtime.h>
#include <hip/hip_bf16.h>
#include <cstdint>
#include <cstddef>

#define DEVFN __device__ __forceinline__

typedef __attribute__((ext_vector_type(4))) float f32x4;
typedef __attribute__((ext_vector_type(8))) short bf16x8;
typedef __attribute__((ext_vector_type(4))) short short4v;

static constexpr int S = 4096;
static constexpr int H = 3584;
static constexpr int NQ = 16;
static constexpr int NKV = 8;
static constexpr int D = 256;
static constexpr int WINDOW = 2048;
static constexpr float SCALE = 0.0625f;  // 256^-0.5

DEVFN unsigned short f2bf(float f) {
  union { float f; uint32_t u; } x; x.f = f;
  uint32_t u = x.u;
  u += 0x7fffu + ((u >> 16) & 1u);   // RNE
  return (unsigned short)(u >> 16);
}
DEVFN float bf2f(unsigned short h) {
  union { uint32_t u; float f; } x; x.u = ((uint32_t)h) << 16;
  return x.f;
}

DEVFN void load_lds16(const void* g, void* l) {
  __builtin_amdgcn_global_load_lds((const __attribute__((address_space(1))) void*)g,
                                   (__attribute__((address_space(3))) void*)l,
                                   16, 0, 0);
}

// ---------------- elementwise cast: hs f32 -> bf16 ----------------
__global__ __launch_bounds__(256) void cast_hs_kernel(const float* __restrict__ in,
                                                      unsigned short* __restrict__ out) {
  int i = (blockIdx.x * 256 + threadIdx.x) * 4;
  float4 v = *(const float4*)(in + i);
  short4v o;
  o[0] = (short)f2bf(v.x); o[1] = (short)f2bf(v.y);
  o[2] = (short)f2bf(v.z); o[3] = (short)f2bf(v.w);
  *(short4v*)(out + i) = o;
}

// ---------------- transpose + cast: w[K][N] f32 -> wT[N][K] bf16 ----------------
__global__ void transpose_cast_kernel(const float* __restrict__ in, unsigned short* __restrict__ out,
                                      int rows, int cols, int out_ld) {
  __shared__ float tile[32][33];
  int r0 = blockIdx.y * 32, c0 = blockIdx.x * 32;
  int tx = threadIdx.x, ty = threadIdx.y;  // 32 x 8
#pragma unroll
  for (int j = 0; j < 32; j += 8)
    tile[ty + j][tx] = in[(size_t)(r0 + ty + j) * cols + (c0 + tx)];
  __syncthreads();
#pragma unroll
  for (int j = 0; j < 32; j += 8)
    out[(size_t)(c0 + ty + j) * out_ld + (r0 + tx)] = f2bf(tile[tx][ty + j]);
}

// ---------------- RoPE cos/sin table [S][128] x2 f32 ----------------
__global__ __launch_bounds__(256) void rope_table_kernel(float* __restrict__ cs) {
  int idx = blockIdx.x * 256 + threadIdx.x;  // S*128
  int s = idx >> 7, i = idx & 127;
  float inv = 1.0f / powf(10000.0f, (float)i * (1.0f / 128.0f));
  float f = (float)s * inv;
  cs[idx] = cosf(f);
  cs[(S * 128) + idx] = sinf(f);
}

// ---------------- RoPE apply in-place on q and k (bf16), 4 elems/thread ----------------
__global__ __launch_bounds__(256) void rope_apply_kernel(unsigned short* __restrict__ q,
                                                         unsigned short* __restrict__ k,
                                                         const float* __restrict__ cs) {
  int idx = blockIdx.x * 256 + threadIdx.x;   // (NQ+NKV)*S*32
  int i4 = (idx & 31) * 4;
  int s = (idx >> 5) & (S - 1);
  int hh = idx >> 17;
  unsigned short* base = (hh < NQ) ? (q + ((size_t)hh * S + s) * D)
                                   : (k + ((size_t)(hh - NQ) * S + s) * D);
  float4 c  = *(const float4*)(cs + (s << 7) + i4);
  float4 sn = *(const float4*)(cs + (S * 128) + (s << 7) + i4);
  short4v a = *(short4v*)(base + i4);
  short4v b = *(short4v*)(base + i4 + 128);
  short4v o1, o2;
  o1[0] = (short)f2bf(bf2f((unsigned short)a[0]) * c.x - bf2f((unsigned short)b[0]) * sn.x);
  o1[1] = (short)f2bf(bf2f((unsigned short)a[1]) * c.y - bf2f((unsigned short)b[1]) * sn.y);
  o1[2] = (short)f2bf(bf2f((unsigned short)a[2]) * c.z - bf2f((unsigned short)b[2]) * sn.z);
  o1[3] = (short)f2bf(bf2f((unsigned short)a[3]) * c.w - bf2f((unsigned short)b[3]) * sn.w);
  o2[0] = (short)f2bf(bf2f((unsigned short)b[0]) * c.x + bf2f((unsigned short)a[0]) * sn.x);
  o2[1] = (short)f2bf(bf2f((unsigned short)b[1]) * c.y + bf2f((unsigned short)a[1]) * sn.y);
  o2[2] = (short)f2bf(bf2f((unsigned short)b[2]) * c.z + bf2f((unsigned short)a[2]) * sn.z);
  o2[3] = (short)f2bf(bf2f((unsigned short)b[3]) * c.w + bf2f((unsigned short)a[3]) * sn.w);
  *(short4v*)(base + i4) = o1;
  *(short4v*)(base + i4 + 128) = o2;
}

// ================== 256x256 8-phase GEMM (T2+T3+T4+T5) ==================
// 512 threads = 8 waves (2M x 4N), per-wave output 128x64. BK=64 in 2 k-halves.
// LDS (dynamic, 128 KiB): [buf(2)][mat(2: A,B)][kh(2)][16384B]
//   region layout: logical (row 0..255, kbyte c 0..63) ->
//   L = (row&127)*128 + ((c + (row>>7)*64) ^ ((row&7)<<4))   (bijective, conflict-free reads)
// Staged via global_load_lds (linear dest = tid*16 + j*8192) with inverse-swizzled
// global source. Counted vmcnt(4) once per K-tile; raw s_barrier (no vmcnt(0) drain).
DEVFN void gemm256_mainloop(const unsigned short* __restrict__ A,
                            const unsigned short* __restrict__ Bt,
                            int Kdim, int lda, int ldb, int row0, int col0,
                            char* lds, f32x4 acc[8][4]) {
  const int tid = threadIdx.x, lane = tid & 63;
  const int w = tid >> 6;
  const int wm = w >> 2, wn = w & 3;
  const int NT = Kdim >> 6;

  // staging decode: LDS offset o = j*8192 + tid*16 -> logical (row, c)
  const int u = ((tid & 7) * 16) ^ (((tid >> 3) & 7) << 4);
  const int srow = (tid >> 3) + (u >> 6) * 128;   // j=1 adds 64
  const int sc = (u & 63) >> 1;                   // element within k-half

  const unsigned short* aSrc = A + (size_t)(row0 + srow) * lda + sc;
  const unsigned short* bSrc = Bt + (size_t)(col0 + srow) * ldb + sc;
  const size_t aj = (size_t)64 * lda, bj = (size_t)64 * ldb;

  char* const dA = lds + tid * 16;
  char* const dB = lds + 32768 + tid * 16;

  // fragment read offsets (conflict-free: XOR spreads 8 rows over 8 16B slots)
  const int aoff = (lane & 15) * 128 + ((((lane >> 4) * 16) + wm * 64) ^ ((lane & 7) << 4));
  const int boff = ((wn & 1) * 64 + (lane & 15)) * 128 +
                   ((((lane >> 4) * 16) + (wn >> 1) * 64) ^ ((lane & 7) << 4));

#define STAGE_A(kt2, kh) do { \
    char* d_ = dA + (((kt2) & 1) << 16) + ((kh) << 14); \
    const unsigned short* s_ = aSrc + (kt2) * 64 + (kh) * 32; \
    load_lds16(s_, d_); load_lds16(s_ + aj, d_ + 8192); } while (0)
#define STAGE_B(kt2, kh) do { \
    char* d_ = dB + (((kt2) & 1) << 16) + ((kh) << 14); \
    const unsigned short* s_ = bSrc + (kt2) * 64 + (kh) * 32; \
    load_lds16(s_, d_); load_lds16(s_ + bj, d_ + 8192); } while (0)

  // prologue: kt0.{A0,B0,A1,B1} + kt1.{A0,B0} = 12 loads; wait kt0 landed (4 left)
  STAGE_A(0, 0); STAGE_B(0, 0); STAGE_A(0, 1); STAGE_B(0, 1);
  if (NT > 1) { STAGE_A(1, 0); STAGE_B(1, 0); }
  asm volatile("s_waitcnt vmcnt(4)" ::: "memory");
  __builtin_amdgcn_s_barrier();
  asm volatile("" ::: "memory");

  for (int kt = 0; kt < NT; ++kt) {
    const char* lA = lds + ((kt & 1) << 16) + aoff;
    const char* lB = lds + ((kt & 1) << 16) + 32768 + boff;
    bf16x8 bfr[4];
#pragma unroll
    for (int ph = 0; ph < 4; ++ph) {
      const int kh = ph >> 1;    // k-half consumed this phase
      const int mh = ph & 1;     // m-half computed this phase
      bf16x8 af[4];
#pragma unroll
      for (int j = 0; j < 4; ++j)
        af[j] = *(const bf16x8*)(lA + (kh << 14) + (mh * 4 + j) * 2048);
      if (mh == 0) {
#pragma unroll
        for (int n = 0; n < 4; ++n)
          bfr[n] = *(const bf16x8*)(lB + (kh << 14) + n * 2048);
      }
      // stage exactly one half-tile per phase (targets proven read-dead regions)
      if (ph == 0)      { if (kt + 1 < NT) STAGE_A(kt + 1, 1); }
      else if (ph == 1) { if (kt + 1 < NT) STAGE_B(kt + 1, 1); }
      else if (ph == 2) { if (kt + 2 < NT) STAGE_A(kt + 2, 0); }
      else              { if (kt + 2 < NT) STAGE_B(kt + 2, 0); }

      asm volatile("" ::: "memory");
      __builtin_amdgcn_s_barrier();
      asm volatile("" ::: "memory");
      __builtin_amdgcn_s_setprio(1);
#pragma unroll
      for (int j = 0; j < 4; ++j)
#pragma unroll
        for (int n = 0; n < 4; ++n)
          acc[mh * 4 + j][n] =
              __builtin_amdgcn_mfma_f32_16x16x32_bf16(af[j], bfr[n], acc[mh * 4 + j][n], 0, 0, 0);
      __builtin_amdgcn_s_setprio(0);
      if (ph == 3) {
        if (kt < NT - 2) asm volatile("s_waitcnt vmcnt(4)" ::: "memory");
        else             asm volatile("s_waitcnt vmcnt(0)" ::: "memory");
      }
      asm volatile("" ::: "memory");
      __builtin_amdgcn_s_barrier();
      asm volatile("" ::: "memory");
    }
  }
#undef STAGE_A
#undef STAGE_B
}

// ---------------- GEMM 1: [S][H] x [H][8192] -> scatter to q, k, vt ----------------
__global__ __launch_bounds__(512, 2) void gemm_qkv_kernel(const unsigned short* __restrict__ A,
                                                          const unsigned short* __restrict__ Bt,
                                                          unsigned short* __restrict__ qb,
                                                          unsigned short* __restrict__ kbuf,
                                                          unsigned short* __restrict__ vtb) {
  extern __shared__ char lds[];
  int bid = blockIdx.x;                 // 512 blocks
  bid = (bid & 7) * 64 + (bid >> 3);    // bijective XCD swizzle (512 % 8 == 0)
  const int bx = bid & 15, by = bid >> 4;
  const int row0 = bx * 256, col0 = by * 256;
  f32x4 acc[8][4];
  f32x4 z = {0.f, 0.f, 0.f, 0.f};
#pragma unroll
  for (int m = 0; m < 8; ++m)
#pragma unroll
    for (int n = 0; n < 4; ++n) acc[m][n] = z;

  gemm256_mainloop(A, Bt, H, H, H, row0, col0, lds, acc);

  const int lane = threadIdx.x & 63, w = threadIdx.x >> 6;
  const int wm = w >> 2, wn = w & 3;
  const int rbase = row0 + wm * 128 + (lane >> 4) * 4;
  const int cbase = col0 + wn * 64 + (lane & 15);
  if (col0 < 4096) {            // Q block
#pragma unroll
    for (int m = 0; m < 8; ++m)
#pragma unroll
      for (int n = 0; n < 4; ++n)
#pragma unroll
        for (int r = 0; r < 4; ++r) {
          int row = rbase + m * 16 + r;
          int col = cbase + n * 16;
          qb[((size_t)(col >> 8) * S + row) * D + (col & 255)] = f2bf(acc[m][n][r]);
        }
  } else if (col0 < 6144) {     // K block
#pragma unroll
    for (int m = 0; m < 8; ++m)
#pragma unroll
      for (int n = 0; n < 4; ++n)
#pragma unroll
        for (int r = 0; r < 4; ++r) {
          int row = rbase + m * 16 + r;
          int c2 = cbase + n * 16 - 4096;
          kbuf[((size_t)(c2 >> 8) * S + row) * D + (c2 & 255)] = f2bf(acc[m][n][r]);
        }
  } else {                      // V block (store transposed)
#pragma unroll
    for (int m = 0; m < 8; ++m)
#pragma unroll
      for (int n = 0; n < 4; ++n)
#pragma unroll
        for (int r = 0; r < 4; ++r) {
          int row = rbase + m * 16 + r;
          int c3 = cbase + n * 16 - 6144;
          vtb[((size_t)(c3 >> 8) * D + (c3 & 255)) * S + row] = f2bf(acc[m][n][r]);
        }
  }
}

// ---------------- GEMM 2: attn_out[S][4096] x woT[H rows][4096] -> d_out f32 ----------------
__global__ __launch_bounds__(512, 2) void gemm_out_kernel(const unsigned short* __restrict__ A,
                                                          const unsigned short* __restrict__ Bt,
                                                          float* __restrict__ C) {
  extern __shared__ char lds[];
  int bid = blockIdx.x;                 // 224 blocks
  bid = (bid & 7) * 28 + (bid >> 3);    // bijective (224 % 8 == 0)
  const int bx = bid & 15, by = bid >> 4;
  const int row0 = bx * 256, col0 = by * 256;
  f32x4 acc[8][4];
  f32x4 z = {0.f, 0.f, 0.f, 0.f};
#pragma unroll
  for (int m = 0; m < 8; ++m)
#pragma unroll
    for (int n = 0; n < 4; ++n) acc[m][n] = z;

  gemm256_mainloop(A, Bt, NQ * D, NQ * D, NQ * D, row0, col0, lds, acc);

  const int lane = threadIdx.x & 63, w = threadIdx.x >> 6;
  const int wm = w >> 2, wn = w & 3;
  const int rbase = row0 + wm * 128 + (lane >> 4) * 4;
  const int cbase = col0 + wn * 64 + (lane & 15);
#pragma unroll
  for (int m = 0; m < 8; ++m)
#pragma unroll
    for (int n = 0; n < 4; ++n)
#pragma unroll
      for (int r = 0; r < 4; ++r)
        C[(size_t)(rbase + m * 16 + r) * H + cbase + n * 16] = acc[m][n][r];
}

// ---------------- flash attention, sliding window + softcap, GQA ----------------
__global__ __launch_bounds__(256) void attn_kernel(const unsigned short* __restrict__ q,
                                                   const unsigned short* __restrict__ kk_,
                                                   const unsigned short* __restrict__ vt,
                                                   unsigned short* __restrict__ aout) {
  __shared__ __align__(16) char kl[2][16384];  // K tile [32 keys][256 d] bf16, swizzled
  __shared__ __align__(16) char vl[2][16384];  // Vt tile [256 d][32 keys] bf16, swizzled
  __shared__ __align__(16) char pl[4096];      // P per wave [16 q][32 keys] bf16, swizzled
  const int tid = threadIdx.x, lane = tid & 63, w = tid >> 6;
  const int h = blockIdx.y, hv = h >> 1;    // N_REP = 2
  const int q0 = blockIdx.x * 64;
  const int ql = lane & 15;
  const int grp = lane >> 4;
  const int qg = q0 + w * 16 + ql;

  bf16x8 qf[8];
  const unsigned short* qrow = q + ((size_t)h * S + qg) * D;
#pragma unroll
  for (int t = 0; t < 8; ++t)
    qf[t] = *(const bf16x8*)(qrow + t * 32 + grp * 8);

  f32x4 oacc[16];
  f32x4 z = {0.f, 0.f, 0.f, 0.f};
#pragma unroll
  for (int i = 0; i < 16; ++i) oacc[i] = z;
  float lrun = 0.0f;

  int lo = q0 - (WINDOW - 1); if (lo < 0) lo = 0;
  const int kb0 = lo & ~31;
  const int kend = q0 + 32;

  const unsigned short* kbase = kk_ + (size_t)hv * S * D;
  const unsigned short* vbase = vt + (size_t)hv * D * S;
  int koff[4], voff[4];
#pragma unroll
  for (int j = 0; j < 4; ++j) {
    int c = w + 4 * j;
    int key = c * 2 + (lane >> 5);
    int colK = (((lane & 31) * 16) ^ ((key & 7) << 4)) >> 1;
    koff[j] = key * D + colK;
    int dd = c * 16 + (lane >> 2);
    int colV = (((lane & 3) * 16) ^ (((dd >> 1) & 3) << 4)) >> 1;
    voff[j] = dd * S + colV;
  }

  auto stage = [&](int buf, int kb) {
#pragma unroll
    for (int j = 0; j < 4; ++j) {
      int c = w + 4 * j;
      load_lds16(kbase + (size_t)kb * D + koff[j], &kl[buf][c * 1024]);
      load_lds16(vbase + kb + voff[j], &vl[buf][c * 1024]);
    }
  };

  stage(0, kb0);
  int cur = 0;
  const int psw = ((ql >> 1) & 3) << 4;
  char* pw = pl + w * 1024;

  for (int kb = kb0; kb <= kend; kb += 32) {
    __syncthreads();
    if (kb + 32 <= kend) stage(cur ^ 1, kb + 32);

    f32x4 sacc[2];
    sacc[0] = z; sacc[1] = z;
#pragma unroll
    for (int mt = 0; mt < 2; ++mt) {
      const int krow = mt * 16 + ql;
      const char* kbp = kl[cur] + krow * 512;
      const int sw = (krow & 7) << 4;
#pragma unroll
      for (int t = 0; t < 8; ++t) {
        bf16x8 a = *(const bf16x8*)(kbp + ((t * 64 + grp * 16) ^ sw));
        sacc[mt] = __builtin_amdgcn_mfma_f32_16x16x32_bf16(a, qf[t], sacc[mt], 0, 0, 0);
      }
    }

    float pv[8];
#pragma unroll
    for (int i = 0; i < 8; ++i) {
      float x = sacc[i >> 2][i & 3];
      float e = __expf(x * (SCALE / 25.0f));
      float rc = __builtin_amdgcn_rcpf(e + 1.0f);
      pv[i] = __expf(rc * -100.0f);
    }
    if (kb + 31 > q0) {
#pragma unroll
      for (int i = 0; i < 8; ++i) {
        int key = kb + (i >> 2) * 16 + grp * 4 + (i & 3);
        if (key > qg) pv[i] = 0.0f;
      }
    } else if (kb < q0 - (WINDOW - 64)) {
#pragma unroll
      for (int i = 0; i < 8; ++i) {
        int key = kb + (i >> 2) * 16 + grp * 4 + (i & 3);
        if (key <= qg - WINDOW) pv[i] = 0.0f;
      }
    }
#pragma unroll
    for (int i = 0; i < 8; ++i) lrun += pv[i];

#pragma unroll
    for (int mt = 0; mt < 2; ++mt) {
      short4v pk;
      pk[0] = (short)f2bf(pv[mt * 4 + 0]);
      pk[1] = (short)f2bf(pv[mt * 4 + 1]);
      pk[2] = (short)f2bf(pv[mt * 4 + 2]);
      pk[3] = (short)f2bf(pv[mt * 4 + 3]);
      *(short4v*)(pw + ql * 64 + ((mt * 32 + grp * 8) ^ psw)) = pk;
    }
    asm volatile("s_waitcnt lgkmcnt(0)" ::: "memory");
    bf16x8 pb = *(const bf16x8*)(pw + ql * 64 + ((grp * 16) ^ psw));

#pragma unroll
    for (int nt = 0; nt < 16; ++nt) {
      int dr = nt * 16 + ql;
      bf16x8 va = *(const bf16x8*)(vl[cur] + dr * 64 + ((grp * 16) ^ (((dr >> 1) & 3) << 4)));
      oacc[nt] = __builtin_amdgcn_mfma_f32_16x16x32_bf16(va, pb, oacc[nt], 0, 0, 0);
    }
    cur ^= 1;
  }

  lrun += __shfl_xor(lrun, 16);
  lrun += __shfl_xor(lrun, 32);
  lrun = fmaxf(lrun, 1e-35f);
  float rl = 1.0f / lrun;
  unsigned short* orow = aout + (size_t)qg * (NQ * D) + h * D;
#pragma unroll
  for (int nt = 0; nt < 16; ++nt) {
    short4v o;
    o[0] = (short)f2bf(oacc[nt][0] * rl);
    o[1] = (short)f2bf(oacc[nt][1] * rl);
    o[2] = (short)f2bf(oacc[nt][2] * rl);
    o[3] = (short)f2bf(oacc[nt][3] * rl);
    *(short4v*)(orow + nt * 16 + grp * 4) = o;
  }
}

// ---------------- launch ----------------
extern "C" void kernel_launch(void* const* d_in, const int* in_sizes, int n_in,
                              void* d_out, int out_size, void* d_ws, size_t ws_size,
                              hipStream_t stream) {
  const float* hs = (const float*)d_in[0];
  const float* wq = (const float*)d_in[1];
  const float* wk = (const float*)d_in[2];
  const float* wv = (const float*)d_in[3];
  const float* wo = (const float*)d_in[4];
  float* out = (float*)d_out;

  char* ws = (char*)d_ws;
  size_t off = 0;
  auto alloc = [&](size_t bytes) {
    char* p = ws + off;
    off += (bytes + 255) & ~(size_t)255;
    return p;
  };
  unsigned short* hsb   = (unsigned short*)alloc((size_t)S * H * 2);
  unsigned short* wqkvT = (unsigned short*)alloc((size_t)8192 * H * 2);
  unsigned short* woT   = (unsigned short*)alloc((size_t)H * 4096 * 2);
  unsigned short* qb    = (unsigned short*)alloc((size_t)NQ * S * D * 2);
  unsigned short* kbuf  = (unsigned short*)alloc((size_t)NKV * S * D * 2);
  unsigned short* vtb   = (unsigned short*)alloc((size_t)NKV * D * S * 2);
  unsigned short* aob   = (unsigned short*)alloc((size_t)S * NQ * D * 2);
  float*          cs    = (float*)alloc((size_t)S * 128 * 2 * 4);
  if (off > ws_size) return;

  dim3 tb(32, 8);
  cast_hs_kernel<<<(S * H) / 1024, 256, 0, stream>>>(hs, hsb);
  transpose_cast_kernel<<<dim3(4096 / 32, H / 32), tb, 0, stream>>>(wq, wqkvT, H, 4096, H);
  transpose_cast_kernel<<<dim3(2048 / 32, H / 32), tb, 0, stream>>>(wk, wqkvT + (size_t)4096 * H, H, 2048, H);
  transpose_cast_kernel<<<dim3(2048 / 32, H / 32), tb, 0, stream>>>(wv, wqkvT + (size_t)6144 * H, H, 2048, H);
  transpose_cast_kernel<<<dim3(H / 32, 4096 / 32), tb, 0, stream>>>(wo, woT, 4096, H, 4096);
  rope_table_kernel<<<(S * 128) / 256, 256, 0, stream>>>(cs);
  gemm_qkv_kernel<<<512, 512, 131072, stream>>>(hsb, wqkvT, qb, kbuf, vtb);
  rope_apply_kernel<<<((NQ + NKV) * S * 32) / 256, 256, 0, stream>>>(qb, kbuf, cs);
  attn_kernel<<<dim3(S / 64, NQ), 256, 0, stream>>>(qb, kbuf, vtb, aob);
  gemm_out_kernel<<<224, 512, 131072, stream>>>(aob, woT, out);
}

// Round 4
// 621.882 us; speedup vs baseline: 1.7511x; 1.0456x over previous
//
#include <hip/hip_runtime.h>
#include <hip/hip_bf16.h>
#include <cstdint>
#include <cstddef>

#define DEVFN __device__ __forceinline__

typedef __attribute__((ext_vector_type(4))) float f32x4;
typedef __attribute__((ext_vector_type(8))) short bf16x8;
typedef __attribute__((ext_vector_type(4))) short short4v;

static constexpr int S = 4096;
static constexpr int H = 3584;
static constexpr int NQ = 16;
static constexpr int NKV = 8;
static constexpr int D = 256;
static constexpr int WINDOW = 2048;
static constexpr float SCALE = 0.0625f;  // 256^-0.5

DEVFN unsigned short f2bf(float f) {
  union { float f; uint32_t u; } x; x.f = f;
  uint32_t u = x.u;
  u += 0x7fffu + ((u >> 16) & 1u);   // RNE
  return (unsigned short)(u >> 16);
}
DEVFN float bf2f(unsigned short h) {
  union { uint32_t u; float f; } x; x.u = ((uint32_t)h) << 16;
  return x.f;
}

DEVFN void load_lds16(const void* g, void* l) {
  __builtin_amdgcn_global_load_lds((const __attribute__((address_space(1))) void*)g,
                                   (__attribute__((address_space(3))) void*)l,
                                   16, 0, 0);
}

// ---------------- elementwise cast: hs f32 -> bf16 ----------------
__global__ __launch_bounds__(256) void cast_hs_kernel(const float* __restrict__ in,
                                                      unsigned short* __restrict__ out) {
  int i = (blockIdx.x * 256 + threadIdx.x) * 4;
  float4 v = *(const float4*)(in + i);
  short4v o;
  o[0] = (short)f2bf(v.x); o[1] = (short)f2bf(v.y);
  o[2] = (short)f2bf(v.z); o[3] = (short)f2bf(v.w);
  *(short4v*)(out + i) = o;
}

// ---------------- transpose + cast: w[K][N] f32 -> wT[N][K] bf16 ----------------
__global__ void transpose_cast_kernel(const float* __restrict__ in, unsigned short* __restrict__ out,
                                      int rows, int cols, int out_ld) {
  __shared__ float tile[32][33];
  int r0 = blockIdx.y * 32, c0 = blockIdx.x * 32;
  int tx = threadIdx.x, ty = threadIdx.y;  // 32 x 8
#pragma unroll
  for (int j = 0; j < 32; j += 8)
    tile[ty + j][tx] = in[(size_t)(r0 + ty + j) * cols + (c0 + tx)];
  __syncthreads();
#pragma unroll
  for (int j = 0; j < 32; j += 8)
    out[(size_t)(c0 + ty + j) * out_ld + (r0 + tx)] = f2bf(tile[tx][ty + j]);
}

// ---------------- RoPE cos/sin table [S][128] x2 f32 ----------------
__global__ __launch_bounds__(256) void rope_table_kernel(float* __restrict__ cs) {
  int idx = blockIdx.x * 256 + threadIdx.x;  // S*128
  int s = idx >> 7, i = idx & 127;
  float inv = 1.0f / powf(10000.0f, (float)i * (1.0f / 128.0f));
  float f = (float)s * inv;
  cs[idx] = cosf(f);
  cs[(S * 128) + idx] = sinf(f);
}

// ---------------- RoPE apply in-place on q and k (bf16), 4 elems/thread ----------------
__global__ __launch_bounds__(256) void rope_apply_kernel(unsigned short* __restrict__ q,
                                                         unsigned short* __restrict__ k,
                                                         const float* __restrict__ cs) {
  int idx = blockIdx.x * 256 + threadIdx.x;   // (NQ+NKV)*S*32
  int i4 = (idx & 31) * 4;
  int s = (idx >> 5) & (S - 1);
  int hh = idx >> 17;
  unsigned short* base = (hh < NQ) ? (q + ((size_t)hh * S + s) * D)
                                   : (k + ((size_t)(hh - NQ) * S + s) * D);
  float4 c  = *(const float4*)(cs + (s << 7) + i4);
  float4 sn = *(const float4*)(cs + (S * 128) + (s << 7) + i4);
  short4v a = *(short4v*)(base + i4);
  short4v b = *(short4v*)(base + i4 + 128);
  short4v o1, o2;
  o1[0] = (short)f2bf(bf2f((unsigned short)a[0]) * c.x - bf2f((unsigned short)b[0]) * sn.x);
  o1[1] = (short)f2bf(bf2f((unsigned short)a[1]) * c.y - bf2f((unsigned short)b[1]) * sn.y);
  o1[2] = (short)f2bf(bf2f((unsigned short)a[2]) * c.z - bf2f((unsigned short)b[2]) * sn.z);
  o1[3] = (short)f2bf(bf2f((unsigned short)a[3]) * c.w - bf2f((unsigned short)b[3]) * sn.w);
  o2[0] = (short)f2bf(bf2f((unsigned short)b[0]) * c.x + bf2f((unsigned short)a[0]) * sn.x);
  o2[1] = (short)f2bf(bf2f((unsigned short)b[1]) * c.y + bf2f((unsigned short)a[1]) * sn.y);
  o2[2] = (short)f2bf(bf2f((unsigned short)b[2]) * c.z + bf2f((unsigned short)a[2]) * sn.z);
  o2[3] = (short)f2bf(bf2f((unsigned short)b[3]) * c.w + bf2f((unsigned short)a[3]) * sn.w);
  *(short4v*)(base + i4) = o1;
  *(short4v*)(base + i4 + 128) = o2;
}

// ================== 256x256 8-phase GEMM (T2+T3+T4+T5) ==================
DEVFN void gemm256_mainloop(const unsigned short* __restrict__ A,
                            const unsigned short* __restrict__ Bt,
                            int Kdim, int lda, int ldb, int row0, int col0,
                            char* lds, f32x4 acc[8][4]) {
  const int tid = threadIdx.x, lane = tid & 63;
  const int w = tid >> 6;
  const int wm = w >> 2, wn = w & 3;
  const int NT = Kdim >> 6;

  const int u = ((tid & 7) * 16) ^ (((tid >> 3) & 7) << 4);
  const int srow = (tid >> 3) + (u >> 6) * 128;
  const int sc = (u & 63) >> 1;

  const unsigned short* aSrc = A + (size_t)(row0 + srow) * lda + sc;
  const unsigned short* bSrc = Bt + (size_t)(col0 + srow) * ldb + sc;
  const size_t aj = (size_t)64 * lda, bj = (size_t)64 * ldb;

  char* const dA = lds + tid * 16;
  char* const dB = lds + 32768 + tid * 16;

  const int aoff = (lane & 15) * 128 + ((((lane >> 4) * 16) + wm * 64) ^ ((lane & 7) << 4));
  const int boff = ((wn & 1) * 64 + (lane & 15)) * 128 +
                   ((((lane >> 4) * 16) + (wn >> 1) * 64) ^ ((lane & 7) << 4));

#define STAGE_A(kt2, kh) do { \
    char* d_ = dA + (((kt2) & 1) << 16) + ((kh) << 14); \
    const unsigned short* s_ = aSrc + (kt2) * 64 + (kh) * 32; \
    load_lds16(s_, d_); load_lds16(s_ + aj, d_ + 8192); } while (0)
#define STAGE_B(kt2, kh) do { \
    char* d_ = dB + (((kt2) & 1) << 16) + ((kh) << 14); \
    const unsigned short* s_ = bSrc + (kt2) * 64 + (kh) * 32; \
    load_lds16(s_, d_); load_lds16(s_ + bj, d_ + 8192); } while (0)

  STAGE_A(0, 0); STAGE_B(0, 0); STAGE_A(0, 1); STAGE_B(0, 1);
  if (NT > 1) { STAGE_A(1, 0); STAGE_B(1, 0); }
  asm volatile("s_waitcnt vmcnt(4)" ::: "memory");
  __builtin_amdgcn_s_barrier();
  asm volatile("" ::: "memory");

  for (int kt = 0; kt < NT; ++kt) {
    const char* lA = lds + ((kt & 1) << 16) + aoff;
    const char* lB = lds + ((kt & 1) << 16) + 32768 + boff;
    bf16x8 bfr[4];
#pragma unroll
    for (int ph = 0; ph < 4; ++ph) {
      const int kh = ph >> 1;
      const int mh = ph & 1;
      bf16x8 af[4];
#pragma unroll
      for (int j = 0; j < 4; ++j)
        af[j] = *(const bf16x8*)(lA + (kh << 14) + (mh * 4 + j) * 2048);
      if (mh == 0) {
#pragma unroll
        for (int n = 0; n < 4; ++n)
          bfr[n] = *(const bf16x8*)(lB + (kh << 14) + n * 2048);
      }
      if (ph == 0)      { if (kt + 1 < NT) STAGE_A(kt + 1, 1); }
      else if (ph == 1) { if (kt + 1 < NT) STAGE_B(kt + 1, 1); }
      else if (ph == 2) { if (kt + 2 < NT) STAGE_A(kt + 2, 0); }
      else              { if (kt + 2 < NT) STAGE_B(kt + 2, 0); }

      asm volatile("" ::: "memory");
      __builtin_amdgcn_s_barrier();
      asm volatile("" ::: "memory");
      __builtin_amdgcn_s_setprio(1);
#pragma unroll
      for (int j = 0; j < 4; ++j)
#pragma unroll
        for (int n = 0; n < 4; ++n)
          acc[mh * 4 + j][n] =
              __builtin_amdgcn_mfma_f32_16x16x32_bf16(af[j], bfr[n], acc[mh * 4 + j][n], 0, 0, 0);
      __builtin_amdgcn_s_setprio(0);
      if (ph == 3) {
        if (kt < NT - 2) asm volatile("s_waitcnt vmcnt(4)" ::: "memory");
        else             asm volatile("s_waitcnt vmcnt(0)" ::: "memory");
      }
      asm volatile("" ::: "memory");
      __builtin_amdgcn_s_barrier();
      asm volatile("" ::: "memory");
    }
  }
#undef STAGE_A
#undef STAGE_B
}

// ---------------- GEMM 1: [S][H] x [H][8192] -> scatter to q, k, vt ----------------
__global__ __launch_bounds__(512, 2) void gemm_qkv_kernel(const unsigned short* __restrict__ A,
                                                          const unsigned short* __restrict__ Bt,
                                                          unsigned short* __restrict__ qb,
                                                          unsigned short* __restrict__ kbuf,
                                                          unsigned short* __restrict__ vtb) {
  extern __shared__ char lds[];
  int bid = blockIdx.x;                 // 512 blocks
  bid = (bid & 7) * 64 + (bid >> 3);    // bijective XCD swizzle
  const int bx = bid & 15, by = bid >> 4;
  const int row0 = bx * 256, col0 = by * 256;
  f32x4 acc[8][4];
  f32x4 z = {0.f, 0.f, 0.f, 0.f};
#pragma unroll
  for (int m = 0; m < 8; ++m)
#pragma unroll
    for (int n = 0; n < 4; ++n) acc[m][n] = z;

  gemm256_mainloop(A, Bt, H, H, H, row0, col0, lds, acc);

  const int lane = threadIdx.x & 63, w = threadIdx.x >> 6;
  const int wm = w >> 2, wn = w & 3;
  const int rbase = row0 + wm * 128 + (lane >> 4) * 4;
  const int cbase = col0 + wn * 64 + (lane & 15);
  if (col0 < 4096) {            // Q block
#pragma unroll
    for (int m = 0; m < 8; ++m)
#pragma unroll
      for (int n = 0; n < 4; ++n)
#pragma unroll
        for (int r = 0; r < 4; ++r) {
          int row = rbase + m * 16 + r;
          int col = cbase + n * 16;
          qb[((size_t)(col >> 8) * S + row) * D + (col & 255)] = f2bf(acc[m][n][r]);
        }
  } else if (col0 < 6144) {     // K block
#pragma unroll
    for (int m = 0; m < 8; ++m)
#pragma unroll
      for (int n = 0; n < 4; ++n)
#pragma unroll
        for (int r = 0; r < 4; ++r) {
          int row = rbase + m * 16 + r;
          int c2 = cbase + n * 16 - 4096;
          kbuf[((size_t)(c2 >> 8) * S + row) * D + (c2 & 255)] = f2bf(acc[m][n][r]);
        }
  } else {                      // V block (store transposed)
#pragma unroll
    for (int m = 0; m < 8; ++m)
#pragma unroll
      for (int n = 0; n < 4; ++n)
#pragma unroll
        for (int r = 0; r < 4; ++r) {
          int row = rbase + m * 16 + r;
          int c3 = cbase + n * 16 - 6144;
          vtb[((size_t)(c3 >> 8) * D + (c3 & 255)) * S + row] = f2bf(acc[m][n][r]);
        }
  }
}

// ---------------- GEMM 2: attn_out[S][4096] x woT[H rows][4096] -> d_out f32 ----------------
__global__ __launch_bounds__(512, 2) void gemm_out_kernel(const unsigned short* __restrict__ A,
                                                          const unsigned short* __restrict__ Bt,
                                                          float* __restrict__ C) {
  extern __shared__ char lds[];
  int bid = blockIdx.x;                 // 224 blocks
  bid = (bid & 7) * 28 + (bid >> 3);
  const int bx = bid & 15, by = bid >> 4;
  const int row0 = bx * 256, col0 = by * 256;
  f32x4 acc[8][4];
  f32x4 z = {0.f, 0.f, 0.f, 0.f};
#pragma unroll
  for (int m = 0; m < 8; ++m)
#pragma unroll
    for (int n = 0; n < 4; ++n) acc[m][n] = z;

  gemm256_mainloop(A, Bt, NQ * D, NQ * D, NQ * D, row0, col0, lds, acc);

  const int lane = threadIdx.x & 63, w = threadIdx.x >> 6;
  const int wm = w >> 2, wn = w & 3;
  const int rbase = row0 + wm * 128 + (lane >> 4) * 4;
  const int cbase = col0 + wn * 64 + (lane & 15);
#pragma unroll
  for (int m = 0; m < 8; ++m)
#pragma unroll
    for (int n = 0; n < 4; ++n)
#pragma unroll
      for (int r = 0; r < 4; ++r)
        C[(size_t)(rbase + m * 16 + r) * H + cbase + n * 16] = acc[m][n][r];
}

// ---------------- flash attention, sliding window + softcap, GQA ----------------
// grid (S/128, NQ), 256 threads = 4 waves; wave w owns 32 q (2 subtiles of 16).
// K/V A-fragments read ONCE per wave and reused across both q-subtiles (2 MFMA/ds_read).
// KVBLK=32, double-buffered K/V, fixed-max softmax (softcap bounds s to +-50).
__global__ __launch_bounds__(256, 2) void attn_kernel(const unsigned short* __restrict__ q,
                                                      const unsigned short* __restrict__ kk_,
                                                      const unsigned short* __restrict__ vt,
                                                      unsigned short* __restrict__ aout) {
  __shared__ __align__(16) char kl[2][16384];  // K tile [32 keys][256 d] bf16, swizzled
  __shared__ __align__(16) char vl[2][16384];  // Vt tile [256 d][32 keys] bf16, swizzled
  __shared__ __align__(16) char pl[8192];      // P per wave [32 q][32 keys] bf16, swizzled
  const int tid = threadIdx.x, lane = tid & 63, w = tid >> 6;
  const int h = blockIdx.y, hv = h >> 1;    // N_REP = 2
  const int q0 = blockIdx.x * 128;
  const int ql = lane & 15;
  const int grp = lane >> 4;
  const int qw = q0 + w * 32;               // wave q base

  // hoist Q fragments for both q-subtiles
  bf16x8 qf[2][8];
#pragma unroll
  for (int qs = 0; qs < 2; ++qs) {
    const unsigned short* qrow = q + ((size_t)h * S + qw + qs * 16 + ql) * D;
#pragma unroll
    for (int t = 0; t < 8; ++t)
      qf[qs][t] = *(const bf16x8*)(qrow + t * 32 + grp * 8);
  }

  f32x4 oacc[2][16];
  f32x4 z = {0.f, 0.f, 0.f, 0.f};
#pragma unroll
  for (int qs = 0; qs < 2; ++qs)
#pragma unroll
    for (int i = 0; i < 16; ++i) oacc[qs][i] = z;
  float lrun[2] = {0.0f, 0.0f};

  int lo = q0 - (WINDOW - 1); if (lo < 0) lo = 0;
  const int kb0 = lo & ~31;
  const int kend = q0 + 96;

  const unsigned short* kbase = kk_ + (size_t)hv * S * D;
  const unsigned short* vbase = vt + (size_t)hv * D * S;
  int koff[4], voff[4];
#pragma unroll
  for (int j = 0; j < 4; ++j) {
    int c = w + 4 * j;
    int key = c * 2 + (lane >> 5);
    int colK = (((lane & 31) * 16) ^ ((key & 7) << 4)) >> 1;
    koff[j] = key * D + colK;
    int dd = c * 16 + (lane >> 2);
    int colV = (((lane & 3) * 16) ^ (((dd >> 1) & 3) << 4)) >> 1;
    voff[j] = dd * S + colV;
  }

  auto stage = [&](int buf, int kb) {
#pragma unroll
    for (int j = 0; j < 4; ++j) {
      int c = w + 4 * j;
      load_lds16(kbase + (size_t)kb * D + koff[j], &kl[buf][c * 1024]);
      load_lds16(vbase + kb + voff[j], &vl[buf][c * 1024]);
    }
  };

  stage(0, kb0);
  int cur = 0;
  const int psw = ((ql >> 1) & 3) << 4;
  char* pw = pl + w * 2048;
  const int ksw = (ql & 7) << 4;

  for (int kb = kb0; kb <= kend; kb += 32) {
    __syncthreads();                       // buf[cur] staged; buf[cur^1] free
    if (kb + 32 <= kend) stage(cur ^ 1, kb + 32);

    // scores^T = K(32x256) x Q^T(256x32): A-frag (K) reused across both q-subs
    f32x4 sacc[2][2];
    sacc[0][0] = z; sacc[0][1] = z; sacc[1][0] = z; sacc[1][1] = z;
#pragma unroll
    for (int t = 0; t < 8; ++t) {
      bf16x8 af[2];
#pragma unroll
      for (int ms = 0; ms < 2; ++ms)
        af[ms] = *(const bf16x8*)(kl[cur] + (ms * 16 + ql) * 512 + ((t * 64 + grp * 16) ^ ksw));
#pragma unroll
      for (int qs = 0; qs < 2; ++qs)
#pragma unroll
        for (int ms = 0; ms < 2; ++ms)
          sacc[qs][ms] = __builtin_amdgcn_mfma_f32_16x16x32_bf16(af[ms], qf[qs][t], sacc[qs][ms], 0, 0, 0);
    }

    // fused softcap+softmax vs fixed max 50: p = exp(-100 / (exp(x*SCALE/25) + 1))
#pragma unroll
    for (int qs = 0; qs < 2; ++qs) {
      const int qsb = qw + qs * 16;
      const int qg = qsb + ql;
      float pv[8];
#pragma unroll
      for (int i = 0; i < 8; ++i) {
        float x = sacc[qs][i >> 2][i & 3];
        float e = __expf(x * (SCALE / 25.0f));
        float rc = __builtin_amdgcn_rcpf(e + 1.0f);
        pv[i] = __expf(rc * -100.0f);
      }
      if (kb + 31 > qsb) {                 // causal edge
#pragma unroll
        for (int i = 0; i < 8; ++i) {
          int key = kb + (i >> 2) * 16 + grp * 4 + (i & 3);
          if (key > qg) pv[i] = 0.0f;
        }
      } else if (kb < qsb - 2032) {        // window edge
#pragma unroll
        for (int i = 0; i < 8; ++i) {
          int key = kb + (i >> 2) * 16 + grp * 4 + (i & 3);
          if (key <= qg - WINDOW) pv[i] = 0.0f;
        }
      }
#pragma unroll
      for (int i = 0; i < 8; ++i) lrun[qs] += pv[i];

      // P -> per-wave LDS [32 q][32 k] (rows 64B, 16B-slot swizzle)
#pragma unroll
      for (int ms = 0; ms < 2; ++ms) {
        short4v pk;
        pk[0] = (short)f2bf(pv[ms * 4 + 0]);
        pk[1] = (short)f2bf(pv[ms * 4 + 1]);
        pk[2] = (short)f2bf(pv[ms * 4 + 2]);
        pk[3] = (short)f2bf(pv[ms * 4 + 3]);
        *(short4v*)(pw + (qs * 16 + ql) * 64 + ((ms * 32 + grp * 8) ^ psw)) = pk;
      }
    }
    asm volatile("s_waitcnt lgkmcnt(0)" ::: "memory");
    bf16x8 pb[2];
#pragma unroll
    for (int qs = 0; qs < 2; ++qs)
      pb[qs] = *(const bf16x8*)(pw + (qs * 16 + ql) * 64 + ((grp * 16) ^ psw));

    // O^T += Vt(256x32) x P^T(32x32): V A-frag reused across both q-subs
#pragma unroll
    for (int nt = 0; nt < 16; ++nt) {
      int dr = nt * 16 + ql;
      bf16x8 va = *(const bf16x8*)(vl[cur] + dr * 64 + ((grp * 16) ^ (((dr >> 1) & 3) << 4)));
      oacc[0][nt] = __builtin_amdgcn_mfma_f32_16x16x32_bf16(va, pb[0], oacc[0][nt], 0, 0, 0);
      oacc[1][nt] = __builtin_amdgcn_mfma_f32_16x16x32_bf16(va, pb[1], oacc[1][nt], 0, 0, 0);
    }
    cur ^= 1;
  }

  // epilogue: reduce l across the 4 lane-groups (same q col), normalize, store
#pragma unroll
  for (int qs = 0; qs < 2; ++qs) {
    float l = lrun[qs];
    l += __shfl_xor(l, 16);
    l += __shfl_xor(l, 32);
    l = fmaxf(l, 1e-35f);
    float rl = 1.0f / l;
    unsigned short* orow = aout + (size_t)(qw + qs * 16 + ql) * (NQ * D) + h * D;
#pragma unroll
    for (int nt = 0; nt < 16; ++nt) {
      short4v o;
      o[0] = (short)f2bf(oacc[qs][nt][0] * rl);
      o[1] = (short)f2bf(oacc[qs][nt][1] * rl);
      o[2] = (short)f2bf(oacc[qs][nt][2] * rl);
      o[3] = (short)f2bf(oacc[qs][nt][3] * rl);
      *(short4v*)(orow + nt * 16 + grp * 4) = o;
    }
  }
}

// ---------------- launch ----------------
extern "C" void kernel_launch(void* const* d_in, const int* in_sizes, int n_in,
                              void* d_out, int out_size, void* d_ws, size_t ws_size,
                              hipStream_t stream) {
  const float* hs = (const float*)d_in[0];
  const float* wq = (const float*)d_in[1];
  const float* wk = (const float*)d_in[2];
  const float* wv = (const float*)d_in[3];
  const float* wo = (const float*)d_in[4];
  float* out = (float*)d_out;

  char* ws = (char*)d_ws;
  size_t off = 0;
  auto alloc = [&](size_t bytes) {
    char* p = ws + off;
    off += (bytes + 255) & ~(size_t)255;
    return p;
  };
  unsigned short* hsb   = (unsigned short*)alloc((size_t)S * H * 2);
  unsigned short* wqkvT = (unsigned short*)alloc((size_t)8192 * H * 2);
  unsigned short* woT   = (unsigned short*)alloc((size_t)H * 4096 * 2);
  unsigned short* qb    = (unsigned short*)alloc((size_t)NQ * S * D * 2);
  unsigned short* kbuf  = (unsigned short*)alloc((size_t)NKV * S * D * 2);
  unsigned short* vtb   = (unsigned short*)alloc((size_t)NKV * D * S * 2);
  unsigned short* aob   = (unsigned short*)alloc((size_t)S * NQ * D * 2);
  float*          cs    = (float*)alloc((size_t)S * 128 * 2 * 4);
  if (off > ws_size) return;

  dim3 tb(32, 8);
  cast_hs_kernel<<<(S * H) / 1024, 256, 0, stream>>>(hs, hsb);
  transpose_cast_kernel<<<dim3(4096 / 32, H / 32), tb, 0, stream>>>(wq, wqkvT, H, 4096, H);
  transpose_cast_kernel<<<dim3(2048 / 32, H / 32), tb, 0, stream>>>(wk, wqkvT + (size_t)4096 * H, H, 2048, H);
  transpose_cast_kernel<<<dim3(2048 / 32, H / 32), tb, 0, stream>>>(wv, wqkvT + (size_t)6144 * H, H, 2048, H);
  transpose_cast_kernel<<<dim3(H / 32, 4096 / 32), tb, 0, stream>>>(wo, woT, 4096, H, 4096);
  rope_table_kernel<<<(S * 128) / 256, 256, 0, stream>>>(cs);
  gemm_qkv_kernel<<<512, 512, 131072, stream>>>(hsb, wqkvT, qb, kbuf, vtb);
  rope_apply_kernel<<<((NQ + NKV) * S * 32) / 256, 256, 0, stream>>>(qb, kbuf, cs);
  attn_kernel<<<dim3(S / 128, NQ), 256, 0, stream>>>(qb, kbuf, vtb, aob);
  gemm_out_kernel<<<224, 512, 131072, stream>>>(aob, woT, out);
}